// Round 2
// baseline (1294.276 us; speedup 1.0000x reference)
//
#include <hip/hip_runtime.h>

// Upsampling 2x nearest-neighbor: (16,64,256,256) fp32 -> (16,64,512,512) fp32.
// Pure data movement. Ideal traffic 1.34 GB -> ~215 us @ 6.3 TB/s.
//
// Harness note (R1 finding): measured dur_us includes a ~690 us poison-fill
// of the 4.3 GB output allocation (rocprof: fillBufferAligned @ 6.24 TB/s).
// Kernel-attributable time in v2 was ~526 us (~2.6 TB/s).
//
// v3: replicate the m13 float4-copy recipe (6.29 TB/s measured on MI355X):
//  - PLAIN cached loads/stores (v2's nontemporal hints regressed vs v1).
//  - 16 B loads (float4), not 8 B: one load -> four 16 B stores.
//  - All 4 stores at immediate offsets {0,16,2048,2064} from ONE base
//    address register; a wave covers one input row and writes BOTH output
//    rows as a single contiguous 4 KB span (v2 emitted 4 disjoint 1 KB
//    chunks from 2 base registers).
//  - Persistent grid 2048x256 (8 blocks/CU), unroll x4, compile-time strides.

using f4v = __attribute__((ext_vector_type(4))) float;

constexpr int B = 16;
constexpr int C = 64;
constexpr int H = 256;
constexpr int W = 256;
constexpr int SCALE = 2;

constexpr int IN_V4_PER_ROW  = W / 4;              // 64 float4 per input row
constexpr int OUT_V4_PER_ROW = (W * SCALE) / 4;    // 128 float4 per output row
constexpr long long N_IN_V4 = (long long)B * C * H * IN_V4_PER_ROW; // 16,777,216

constexpr int BLOCK = 256;
constexpr int GRID  = 2048;                                 // 8 blocks/CU
constexpr long long NTHREADS = (long long)BLOCK * GRID;     // 524,288
constexpr int ITERS  = (int)(N_IN_V4 / NTHREADS);           // 32
constexpr int UNROLL = 4;

static_assert(N_IN_V4 % NTHREADS == 0, "no tail");
static_assert(ITERS % UNROLL == 0, "clean unroll");
static_assert(NTHREADS % IN_V4_PER_ROW == 0, "col loop-invariant");

// Per grid-stride step: input advances NTHREADS float4 = 8192 input rows;
// output advances 8192*SCALE rows of 128 float4.
constexpr long long IN_STEP  = NTHREADS;                                  // f4 units
constexpr long long OUT_STEP =
    (NTHREADS / IN_V4_PER_ROW) * (long long)SCALE * OUT_V4_PER_ROW;       // 2,097,152

__global__ __launch_bounds__(BLOCK)
void Upsampling_68882685493276_kernel(const f4v* __restrict__ in,
                                      f4v* __restrict__ out) {
    const long long t0 = (long long)blockIdx.x * BLOCK + threadIdx.x;
    const int c       = (int)(t0 & (IN_V4_PER_ROW - 1));  // loop-invariant col
    const long long r = t0 >> 6;                          // input row

    const f4v* ip = in + t0;
    // Lane base: output row 2r, col 2c (float4 units). The 4 stores land at
    // byte offsets 0, 16, 2048, 2064 -> all fold into the 13-bit imm offset.
    f4v* op = out + r * (SCALE * OUT_V4_PER_ROW) + 2 * c;

    for (int k = 0; k < ITERS; k += UNROLL) {
        f4v v[UNROLL];
        #pragma unroll
        for (int u = 0; u < UNROLL; ++u)
            v[u] = ip[(long long)u * IN_STEP];

        #pragma unroll
        for (int u = 0; u < UNROLL; ++u) {
            f4v lo = {v[u].x, v[u].x, v[u].y, v[u].y};
            f4v hi = {v[u].z, v[u].z, v[u].w, v[u].w};
            f4v* p = op + (long long)u * OUT_STEP;
            p[0]                   = lo;   // row 2r,   cols [4c, 4c+4)
            p[1]                   = hi;   // row 2r,   cols [4c+4, 4c+8)
            p[OUT_V4_PER_ROW]      = lo;   // row 2r+1, same cols
            p[OUT_V4_PER_ROW + 1]  = hi;
        }

        ip += (long long)UNROLL * IN_STEP;
        op += (long long)UNROLL * OUT_STEP;
    }
}

extern "C" void kernel_launch(void* const* d_in, const int* in_sizes, int n_in,
                              void* d_out, int out_size, void* d_ws, size_t ws_size,
                              hipStream_t stream) {
    const f4v* in = (const f4v*)d_in[0];
    f4v* out = (f4v*)d_out;
    Upsampling_68882685493276_kernel<<<dim3(GRID), dim3(BLOCK), 0, stream>>>(in, out);
}